// Round 10
// baseline (80.957 us; speedup 1.0000x reference)
//
#include <hip/hip_runtime.h>
#include <hip/hip_bf16.h>

// Sizes (fixed by the reference)
#define BB 64
#define AA 128
#define FF 32
#define HH 64

typedef float  f32x4  __attribute__((ext_vector_type(4)));
typedef float  f32x16 __attribute__((ext_vector_type(16)));
typedef __bf16 bf16x8 __attribute__((ext_vector_type(8)));
typedef unsigned int uint4v __attribute__((ext_vector_type(4)));

// ws layout (float offsets)
#define OFF_HIP   0          // hi_p fp32 [B*A][64]  (pair_b1 folded in)
#define OFF_HJ    524288     // hj   fp32 [B*A][64]
#define OFF_BU    1048576    // base_u [B*A]
#define OFF_UTIL  1056768    // util [B*A]
#define OFF_W2FH  1064960    // W2 frag hi: [8 fid][64 lane][8 ushort] = 8 KB
#define OFF_W2FL  1067008    // W2 frag lo
#define OFF_JLIST 1069056    // active-index list [B][128] int
#define OFF_JCNT  1077248    // [B] int

static __device__ __forceinline__ unsigned short f2b_rne(float x) {
    __hip_bfloat16 h = __float2bfloat16(x);
    return __builtin_bit_cast(unsigned short, h);
}
static __device__ __forceinline__ float b2f(unsigned short u) {
    unsigned v = ((unsigned)u) << 16;
    return __builtin_bit_cast(float, v);
}

// ---------------- Kernel 1: features + active-list + W2 frag split --------
__global__ __launch_bounds__(64)
void ddc_features(const float* __restrict__ X, const int* __restrict__ mask,
                  const float* __restrict__ bW1, const float* __restrict__ bb1,
                  const float* __restrict__ bW2, const float* __restrict__ bb2,
                  const float* __restrict__ bW3, const float* __restrict__ bb3,
                  const float* __restrict__ pW1, const float* __restrict__ pb1,
                  const float* __restrict__ pW2,
                  float* __restrict__ hi_p, float* __restrict__ hj,
                  float* __restrict__ base_u,
                  unsigned short* __restrict__ W2fh,
                  unsigned short* __restrict__ W2fl,
                  int* __restrict__ jlist, int* __restrict__ jcnt) {
    const int a = blockIdx.x, b = blockIdx.y, lane = threadIdx.x;
    const int row = b * AA + a;

    // X row is wave-uniform -> scalar loads
    const float* __restrict__ x = X + row * FF;
    float xr[FF];
#pragma unroll
    for (int f = 0; f < FF; ++f) xr[f] = x[f];

    float vhi = pb1[lane];      // fold pair_b1 into hi
    float vhj = 0.f;
    float v1  = bb1[lane];
#pragma unroll
    for (int f = 0; f < FF; ++f) {
        vhi = fmaf(xr[f], pW1[f * HH + lane], vhi);
        vhj = fmaf(xr[f], pW1[(FF + f) * HH + lane], vhj);
        v1  = fmaf(xr[f], bW1[f * HH + lane], v1);
    }
    v1 = fmaxf(v1, 0.f);

    // hb2 = relu(hb1 @ bW2 + bb2): broadcast hb1 across lanes via shuffles
    float v2 = bb2[lane];
#pragma unroll
    for (int k = 0; k < HH; ++k) {
        float hk = __shfl(v1, k);
        v2 = fmaf(hk, bW2[k * HH + lane], v2);
    }
    v2 = fmaxf(v2, 0.f);

    float bu = v2 * bW3[lane];
#pragma unroll
    for (int off = 32; off; off >>= 1) bu += __shfl_xor(bu, off);

    hi_p[row * HH + lane] = vhi;
    hj  [row * HH + lane] = vhj;
    if (lane == 0) base_u[row] = bu + bb3[0];

    // one block per b builds the compacted active-index list
    if (a == 0) {
        int base0 = 0;
#pragma unroll
        for (int hlf = 0; hlf < 2; ++hlf) {
            int idx = hlf * 64 + lane;
            int m = mask[b * AA + idx];
            unsigned long long bal = __ballot(m != 0);
            int pos = __popcll(bal & ((1ull << lane) - 1ull));
            if (m) jlist[b * AA + base0 + pos] = idx;
            base0 += (int)__popcll(bal);
        }
        if (lane == 0) jcnt[b] = base0;
    }

    // one block writes W2 hi/lo in MFMA B-fragment order:
    // fid = nt*4+ks; lane supplies col n = nt*32+(lane&31),
    // k = ks*16 + (lane>>5)*8 + e  (matches mfma_f32_32x32x16_bf16 B layout)
    if (a == 1 && b == 0) {
        const int col = lane & 31, half = lane >> 5;
#pragma unroll
        for (int fid = 0; fid < 8; ++fid) {
            const int nt = fid >> 2, ks = fid & 3;
            const int n = nt * 32 + col;
            const int ko = ks * 16 + half * 8;
#pragma unroll
            for (int e = 0; e < 8; ++e) {
                float w = pW2[(ko + e) * HH + n];
                unsigned short uh = f2b_rne(w);
                W2fh[(fid * 64 + lane) * 8 + e] = uh;
                W2fl[(fid * 64 + lane) * 8 + e] = f2b_rne(w - b2f(uh));
            }
        }
    }
}

// ---------------- Kernel 2: pairwise MLP via split-bf16 MFMA --------------
// R10 restructure vs R9 (which was latency-bound at 9.5% occupancy):
//  * grid (8,64) = 512 blocks = EXACTLY 2 blocks/CU -> whole kernel is one
//    residency generation (8 waves/CU), no dispatch churn, staging amortized
//    over 8 i's per block.
//  * each wave processes TWO i's concurrently: shared sHJ ds_reads + shared
//    AGPR B-frags, 4 independent MFMA chains + 2 VALU streams (2x ILP).
// Registers: arch = yvA+yvB(64)+transients ~115 <=128; accum = B(64)+acc(64)
// = 128. (256,2) keeps both sides inside the 256 cap -> no spill.
#define SPLIT_PAIR(pa, pb, outh, outl)                                   \
    {   unsigned ua = __builtin_bit_cast(unsigned, pa);                  \
        unsigned ub = __builtin_bit_cast(unsigned, pb);                  \
        outh = (ua >> 16) | (ub & 0xFFFF0000u);                          \
        float ra = pa - __builtin_bit_cast(float, ua & 0xFFFF0000u);     \
        float rb = pb - __builtin_bit_cast(float, ub & 0xFFFF0000u);     \
        unsigned va = __builtin_bit_cast(unsigned, ra);                  \
        unsigned vb = __builtin_bit_cast(unsigned, rb);                  \
        outl = (va >> 16) | (vb & 0xFFFF0000u); }

__global__ __launch_bounds__(256, 2)
void ddc_pairs_mfma(const float* __restrict__ hi_p, const float* __restrict__ hj,
                    const float* __restrict__ base_u, const int* __restrict__ mask,
                    const int* __restrict__ jlist, const int* __restrict__ jcnt,
                    const unsigned short* __restrict__ W2fh,
                    const unsigned short* __restrict__ W2fl,
                    const float* __restrict__ pb2, const float* __restrict__ pW3,
                    const float* __restrict__ pb3, float* __restrict__ util) {
    __shared__ float sHJ[AA][HH + 4];   // 34816 B

    const int t  = threadIdx.x;
    const int gx = blockIdx.x;          // 0..7
    const int b  = blockIdx.y;
    const int cnt = jcnt[b];
    const int ngroups = (cnt + 7) >> 3;   // groups of 8 i-slots
    if (gx >= ngroups) return;            // idle block: exit BEFORE staging

    // stage hj rows for this b (coalesced f32x4)
    {
        const int r = t >> 1, hf = t & 1;
        const f32x4* __restrict__ src =
            (const f32x4*)(hj + (b * AA + r) * HH + hf * 32);
        f32x4* dst = (f32x4*)&sHJ[r][hf * 32];
#pragma unroll
        for (int q = 0; q < 8; ++q) dst[q] = src[q];
    }
    __syncthreads();

    const int l = t & 63, wid = t >> 6;
    const int col = l & 31, half = l >> 5;

    // base mask bitsets (per-wave, diagonal cleared per-i inside the loop)
    const unsigned long long mbase0 = __ballot(mask[b * AA + l] != 0);
    const unsigned long long mbase1 = __ballot(mask[b * AA + 64 + l] != 0);

    // B-fragments: load once, PIN INTO AGPRs (accum side of the reg file)
#define LOADB(nt, ks, vh, vl)                                               \
    uint4v vh = *(const uint4v*)(W2fh + (((nt) * 4 + (ks)) * 64 + l) * 8);  \
    uint4v vl = *(const uint4v*)(W2fl + (((nt) * 4 + (ks)) * 64 + l) * 8);  \
    asm("" : "+a"(vh));                                                     \
    asm("" : "+a"(vl));
    LOADB(0, 0, bh00, bl00)
    LOADB(0, 1, bh01, bl01)
    LOADB(0, 2, bh02, bl02)
    LOADB(0, 3, bh03, bl03)
    LOADB(1, 0, bh10, bl10)
    LOADB(1, 1, bh11, bl11)
    LOADB(1, 2, bh12, bl12)
    LOADB(1, 3, bh13, bl13)
#undef LOADB

    const float b2v0 = pb2[col], b2v1 = pb2[32 + col];
    const float w3v0 = pW3[col], w3v1 = pW3[32 + col];
    const float b3s  = pb3[0] * (1.f / 32.f);   // b3 spread over 32 col-lanes

    for (int g = gx; g < ngroups; g += 8) {
        const int s0 = g * 8 + wid * 2;
        if (s0 >= cnt) continue;              // idle wave for this group
        const int s1 = s0 + 1;
        const bool has1 = (s1 < cnt);
        const int i0 = __builtin_amdgcn_readfirstlane(jlist[b * AA + s0]);
        const int i1 = has1 ? __builtin_amdgcn_readfirstlane(jlist[b * AA + s1]) : i0;

        // per-i mask bits with diagonal cleared
        unsigned long long mA0 = mbase0, mA1 = mbase1;
        if (i0 < 64) mA0 &= ~(1ull << i0); else mA1 &= ~(1ull << (i0 - 64));
        unsigned long long mB0 = mbase0, mB1 = mbase1;
        if (i1 < 64) mB0 &= ~(1ull << i1); else mB1 &= ~(1ull << (i1 - 64));

        // hi slices for both i (32 floats each)
        const float* __restrict__ hpA = hi_p + (b * AA + i0) * HH;
        const float* __restrict__ hpB = hi_p + (b * AA + i1) * HH;
        f32x4 yvA[8], yvB[8];
#pragma unroll
        for (int ks = 0; ks < 4; ++ks) {
            const int ko = ks * 16 + half * 8;
            yvA[2 * ks]     = *(const f32x4*)(hpA + ko);
            yvA[2 * ks + 1] = *(const f32x4*)(hpA + ko + 4);
            yvB[2 * ks]     = *(const f32x4*)(hpB + ko);
            yvB[2 * ks + 1] = *(const f32x4*)(hpB + ko + 4);
        }

        float tsumA = 0.f, tsumB = 0.f;
#pragma unroll
        for (int jt = 0; jt < 4; ++jt) {
            f32x16 accA0 = 0.f, accA1 = 0.f, accB0 = 0.f, accB1 = 0.f;
            const int jj = jt * 32 + col;

#define BUILD_A(Y0, Y1, AH, AL)                                             \
            bf16x8 AH, AL;                                                  \
            {   float h0 = fmaxf(x0[0] + (Y0)[0], 0.f);                     \
                float h1 = fmaxf(x0[1] + (Y0)[1], 0.f);                     \
                float h2 = fmaxf(x0[2] + (Y0)[2], 0.f);                     \
                float h3 = fmaxf(x0[3] + (Y0)[3], 0.f);                     \
                float h4 = fmaxf(x1[0] + (Y1)[0], 0.f);                     \
                float h5 = fmaxf(x1[1] + (Y1)[1], 0.f);                     \
                float h6 = fmaxf(x1[2] + (Y1)[2], 0.f);                     \
                float h7 = fmaxf(x1[3] + (Y1)[3], 0.f);                     \
                unsigned a01, a23, a45, a67, c01, c23, c45, c67;            \
                SPLIT_PAIR(h0, h1, a01, c01)                                \
                SPLIT_PAIR(h2, h3, a23, c23)                                \
                SPLIT_PAIR(h4, h5, a45, c45)                                \
                SPLIT_PAIR(h6, h7, a67, c67)                                \
                uint4v ahv = {a01, a23, a45, a67};                          \
                uint4v alv = {c01, c23, c45, c67};                          \
                AH = __builtin_bit_cast(bf16x8, ahv);                       \
                AL = __builtin_bit_cast(bf16x8, alv); }

#define KSTEP(ks, BH0, BL0, BH1, BL1)                                       \
            {   const int ko = (ks) * 16 + half * 8;                        \
                f32x4 x0 = *(const f32x4*)&sHJ[jj][ko];                     \
                f32x4 x1 = *(const f32x4*)&sHJ[jj][ko + 4];                 \
                BUILD_A(yvA[2 * (ks)], yvA[2 * (ks) + 1], ahA, alA)         \
                BUILD_A(yvB[2 * (ks)], yvB[2 * (ks) + 1], ahB, alB)         \
                bf16x8 BH0v = __builtin_bit_cast(bf16x8, BH0);              \
                bf16x8 BL0v = __builtin_bit_cast(bf16x8, BL0);              \
                bf16x8 BH1v = __builtin_bit_cast(bf16x8, BH1);              \
                bf16x8 BL1v = __builtin_bit_cast(bf16x8, BL1);              \
                accA0 = __builtin_amdgcn_mfma_f32_32x32x16_bf16(alA, BH0v, accA0, 0, 0, 0); \
                accB0 = __builtin_amdgcn_mfma_f32_32x32x16_bf16(alB, BH0v, accB0, 0, 0, 0); \
                accA1 = __builtin_amdgcn_mfma_f32_32x32x16_bf16(alA, BH1v, accA1, 0, 0, 0); \
                accB1 = __builtin_amdgcn_mfma_f32_32x32x16_bf16(alB, BH1v, accB1, 0, 0, 0); \
                accA0 = __builtin_amdgcn_mfma_f32_32x32x16_bf16(ahA, BL0v, accA0, 0, 0, 0); \
                accB0 = __builtin_amdgcn_mfma_f32_32x32x16_bf16(ahB, BL0v, accB0, 0, 0, 0); \
                accA1 = __builtin_amdgcn_mfma_f32_32x32x16_bf16(ahA, BL1v, accA1, 0, 0, 0); \
                accB1 = __builtin_amdgcn_mfma_f32_32x32x16_bf16(ahB, BL1v, accB1, 0, 0, 0); \
                accA0 = __builtin_amdgcn_mfma_f32_32x32x16_bf16(ahA, BH0v, accA0, 0, 0, 0); \
                accB0 = __builtin_amdgcn_mfma_f32_32x32x16_bf16(ahB, BH0v, accB0, 0, 0, 0); \
                accA1 = __builtin_amdgcn_mfma_f32_32x32x16_bf16(ahA, BH1v, accA1, 0, 0, 0); \
                accB1 = __builtin_amdgcn_mfma_f32_32x32x16_bf16(ahB, BH1v, accB1, 0, 0, 0); \
            }
            KSTEP(0, bh00, bl00, bh10, bl10)
            KSTEP(1, bh01, bl01, bh11, bl11)
            KSTEP(2, bh02, bl02, bh12, bl12)
            KSTEP(3, bh03, bl03, bh13, bl13)
#undef KSTEP
#undef BUILD_A

            // epilogue for this j-tile: W3 contraction + ballot-bit mask
#pragma unroll
            for (int r = 0; r < 16; ++r) {
                const int rrow = (r & 3) + 8 * (r >> 2) + 4 * half;
                const int sh = (jt & 1) * 32 + rrow;
                float vA = fmaxf(accA0[r] + b2v0, 0.f) * w3v0 +
                           fmaxf(accA1[r] + b2v1, 0.f) * w3v1 + b3s;
                float vB = fmaxf(accB0[r] + b2v0, 0.f) * w3v0 +
                           fmaxf(accB1[r] + b2v1, 0.f) * w3v1 + b3s;
                const unsigned long long bitsA = (jt < 2) ? mA0 : mA1;
                const unsigned long long bitsB = (jt < 2) ? mB0 : mB1;
                tsumA = fmaf(vA, ((bitsA >> sh) & 1ull) ? 1.f : 0.f, tsumA);
                tsumB = fmaf(vB, ((bitsB >> sh) & 1ull) ? 1.f : 0.f, tsumB);
            }
        }
#pragma unroll
        for (int off = 32; off; off >>= 1) {
            tsumA += __shfl_xor(tsumA, off);
            tsumB += __shfl_xor(tsumB, off);
        }
        if (l == 0) {
            util[b * AA + i0] = base_u[b * AA + i0] + tsumA;
            if (has1) util[b * AA + i1] = base_u[b * AA + i1] + tsumB;
        }
    }
}

// ---------------- Kernel 3: per-b masked softmax over A=128 ---------------
__global__ __launch_bounds__(64)
void ddc_softmax(const float* __restrict__ util, const int* __restrict__ mask,
                 float* __restrict__ out) {
    const int b = blockIdx.x, lane = threadIdx.x;
    const int r0 = b * AA + lane, r1 = r0 + 64;
    const float u0 = (mask[r0] != 0) ? util[r0] : -1e9f;
    const float u1 = (mask[r1] != 0) ? util[r1] : -1e9f;

    float m = fmaxf(u0, u1);
#pragma unroll
    for (int off = 32; off; off >>= 1) m = fmaxf(m, __shfl_xor(m, off));

    const float e0 = __expf(u0 - m);
    const float e1 = __expf(u1 - m);
    float s = e0 + e1;
#pragma unroll
    for (int off = 32; off; off >>= 1) s += __shfl_xor(s, off);

    const float inv = 1.f / s;
    out[r0] = e0 * inv;
    out[r1] = e1 * inv;
}

extern "C" void kernel_launch(void* const* d_in, const int* in_sizes, int n_in,
                              void* d_out, int out_size, void* d_ws, size_t ws_size,
                              hipStream_t stream) {
    const float* X    = (const float*)d_in[0];
    const int*   mask = (const int*)  d_in[1];
    const float* bW1  = (const float*)d_in[2];
    const float* bb1  = (const float*)d_in[3];
    const float* bW2  = (const float*)d_in[4];
    const float* bb2  = (const float*)d_in[5];
    const float* bW3  = (const float*)d_in[6];
    const float* bb3  = (const float*)d_in[7];
    const float* pW1  = (const float*)d_in[8];
    const float* pb1  = (const float*)d_in[9];
    const float* pW2  = (const float*)d_in[10];
    const float* pb2  = (const float*)d_in[11];
    const float* pW3  = (const float*)d_in[12];
    const float* pb3  = (const float*)d_in[13];

    float* ws    = (float*)d_ws;
    float* hi_p  = ws + OFF_HIP;
    float* hjW   = ws + OFF_HJ;
    float* baseu = ws + OFF_BU;
    float* util  = ws + OFF_UTIL;
    unsigned short* W2fh = (unsigned short*)(ws + OFF_W2FH);
    unsigned short* W2fl = (unsigned short*)(ws + OFF_W2FL);
    int*   jlist = (int*)(ws + OFF_JLIST);
    int*   jcnt  = (int*)(ws + OFF_JCNT);

    float* out = (float*)d_out;

    dim3 g1(AA, BB);
    ddc_features<<<g1, 64, 0, stream>>>(X, mask, bW1, bb1, bW2, bb2, bW3, bb3,
                                        pW1, pb1, pW2,
                                        hi_p, hjW, baseu, W2fh, W2fl,
                                        jlist, jcnt);
    dim3 g2(8, BB);
    ddc_pairs_mfma<<<g2, 256, 0, stream>>>(hi_p, hjW, baseu, mask, jlist, jcnt,
                                           W2fh, W2fl, pb2, pW3, pb3, util);
    ddc_softmax<<<BB, 64, 0, stream>>>(util, mask, out);
}

// Round 11
// 45.965 us; speedup vs baseline: 1.7613x; 1.7613x over previous
//
#include <hip/hip_runtime.h>
#include <hip/hip_bf16.h>

// Sizes (fixed by the reference)
#define BB 64
#define AA 128
#define FF 32
#define HH 64

typedef float  f32x4  __attribute__((ext_vector_type(4)));
typedef float  f32x16 __attribute__((ext_vector_type(16)));
typedef __bf16 bf16x8 __attribute__((ext_vector_type(8)));
typedef unsigned int uint4v __attribute__((ext_vector_type(4)));

// ws layout (float offsets)
#define OFF_HIP   0          // hi_p fp32 [B*A][64]  (pair_b1 folded in)
#define OFF_HJ    524288     // hj   fp32 [B*A][64]
#define OFF_BU    1048576    // base_u [B*A]
#define OFF_UTIL  1056768    // util [B*A]
#define OFF_W2FH  1064960    // W2 frag hi: [8 fid][64 lane][8 ushort] = 8 KB
#define OFF_W2FL  1067008    // W2 frag lo
#define OFF_JLIST 1069056    // active-index list [B][128] int
#define OFF_JCNT  1077248    // [B] int

static __device__ __forceinline__ unsigned short f2b_rne(float x) {
    __hip_bfloat16 h = __float2bfloat16(x);
    return __builtin_bit_cast(unsigned short, h);
}
static __device__ __forceinline__ float b2f(unsigned short u) {
    unsigned v = ((unsigned)u) << 16;
    return __builtin_bit_cast(float, v);
}

// ---------------- Kernel 1: features + active-list + W2 frag split --------
__global__ __launch_bounds__(64)
void ddc_features(const float* __restrict__ X, const int* __restrict__ mask,
                  const float* __restrict__ bW1, const float* __restrict__ bb1,
                  const float* __restrict__ bW2, const float* __restrict__ bb2,
                  const float* __restrict__ bW3, const float* __restrict__ bb3,
                  const float* __restrict__ pW1, const float* __restrict__ pb1,
                  const float* __restrict__ pW2,
                  float* __restrict__ hi_p, float* __restrict__ hj,
                  float* __restrict__ base_u,
                  unsigned short* __restrict__ W2fh,
                  unsigned short* __restrict__ W2fl,
                  int* __restrict__ jlist, int* __restrict__ jcnt) {
    const int a = blockIdx.x, b = blockIdx.y, lane = threadIdx.x;
    const int row = b * AA + a;

    // X row is wave-uniform -> scalar loads
    const float* __restrict__ x = X + row * FF;
    float xr[FF];
#pragma unroll
    for (int f = 0; f < FF; ++f) xr[f] = x[f];

    float vhi = pb1[lane];      // fold pair_b1 into hi
    float vhj = 0.f;
    float v1  = bb1[lane];
#pragma unroll
    for (int f = 0; f < FF; ++f) {
        vhi = fmaf(xr[f], pW1[f * HH + lane], vhi);
        vhj = fmaf(xr[f], pW1[(FF + f) * HH + lane], vhj);
        v1  = fmaf(xr[f], bW1[f * HH + lane], v1);
    }
    v1 = fmaxf(v1, 0.f);

    // hb2 = relu(hb1 @ bW2 + bb2): broadcast hb1 across lanes via shuffles
    float v2 = bb2[lane];
#pragma unroll
    for (int k = 0; k < HH; ++k) {
        float hk = __shfl(v1, k);
        v2 = fmaf(hk, bW2[k * HH + lane], v2);
    }
    v2 = fmaxf(v2, 0.f);

    float bu = v2 * bW3[lane];
#pragma unroll
    for (int off = 32; off; off >>= 1) bu += __shfl_xor(bu, off);

    hi_p[row * HH + lane] = vhi;
    hj  [row * HH + lane] = vhj;
    if (lane == 0) base_u[row] = bu + bb3[0];

    // one block per b builds the compacted active-index list
    if (a == 0) {
        int base0 = 0;
#pragma unroll
        for (int hlf = 0; hlf < 2; ++hlf) {
            int idx = hlf * 64 + lane;
            int m = mask[b * AA + idx];
            unsigned long long bal = __ballot(m != 0);
            int pos = __popcll(bal & ((1ull << lane) - 1ull));
            if (m) jlist[b * AA + base0 + pos] = idx;
            base0 += (int)__popcll(bal);
        }
        if (lane == 0) jcnt[b] = base0;
    }

    // one block writes W2 hi/lo in MFMA B-fragment order:
    // fid = nt*4+ks; lane supplies col n = nt*32+(lane&31),
    // k = ks*16 + (lane>>5)*8 + e  (matches mfma_f32_32x32x16_bf16 B layout)
    if (a == 1 && b == 0) {
        const int col = lane & 31, half = lane >> 5;
#pragma unroll
        for (int fid = 0; fid < 8; ++fid) {
            const int nt = fid >> 2, ks = fid & 3;
            const int n = nt * 32 + col;
            const int ko = ks * 16 + half * 8;
#pragma unroll
            for (int e = 0; e < 8; ++e) {
                float w = pW2[(ko + e) * HH + n];
                unsigned short uh = f2b_rne(w);
                W2fh[(fid * 64 + lane) * 8 + e] = uh;
                W2fl[(fid * 64 + lane) * 8 + e] = f2b_rne(w - b2f(uh));
            }
        }
    }
}

// ---------------- Kernel 2: pairwise MLP via split-bf16 MFMA --------------
// R11 = R9's proven no-spill wave datapath (1 i/wave, AGPR-pinned B-frags)
// + R10's persistent grid: (8,64) = 512 blocks = EXACTLY 2 blocks/CU, one
// residency generation. Each block stages sHJ ONCE, then loops i-groups
// g = gx, gx+8, ... (4 slots/group, one per wave). Registers: arch = yv(32)
// + transients (~116 total, R9-measured); accum = B(64) + acc(32) = 96.
#define SPLIT_PAIR(pa, pb, outh, outl)                                   \
    {   unsigned ua = __builtin_bit_cast(unsigned, pa);                  \
        unsigned ub = __builtin_bit_cast(unsigned, pb);                  \
        outh = (ua >> 16) | (ub & 0xFFFF0000u);                          \
        float ra = pa - __builtin_bit_cast(float, ua & 0xFFFF0000u);     \
        float rb = pb - __builtin_bit_cast(float, ub & 0xFFFF0000u);     \
        unsigned va = __builtin_bit_cast(unsigned, ra);                  \
        unsigned vb = __builtin_bit_cast(unsigned, rb);                  \
        outl = (va >> 16) | (vb & 0xFFFF0000u); }

__global__ __launch_bounds__(256, 2)
void ddc_pairs_mfma(const float* __restrict__ hi_p, const float* __restrict__ hj,
                    const float* __restrict__ base_u, const int* __restrict__ mask,
                    const int* __restrict__ jlist, const int* __restrict__ jcnt,
                    const unsigned short* __restrict__ W2fh,
                    const unsigned short* __restrict__ W2fl,
                    const float* __restrict__ pb2, const float* __restrict__ pW3,
                    const float* __restrict__ pb3, float* __restrict__ util) {
    __shared__ float sHJ[AA][HH + 4];   // 34816 B

    const int t  = threadIdx.x;
    const int gx = blockIdx.x;            // 0..7
    const int b  = blockIdx.y;
    const int cnt = jcnt[b];
    const int ngroups = (cnt + 3) >> 2;   // groups of 4 i-slots (1 per wave)
    if (gx >= ngroups) return;            // idle block: exit BEFORE staging

    const int l = t & 63, wid = t >> 6;
    const int col = l & 31, half = l >> 5;

    // B-fragment global loads issued FIRST (latency hides under staging);
    // pinned into AGPRs after the barrier.
#define LOADB(nt, ks, vh, vl)                                               \
    uint4v vh = *(const uint4v*)(W2fh + (((nt) * 4 + (ks)) * 64 + l) * 8);  \
    uint4v vl = *(const uint4v*)(W2fl + (((nt) * 4 + (ks)) * 64 + l) * 8);
    LOADB(0, 0, bh00, bl00)
    LOADB(0, 1, bh01, bl01)
    LOADB(0, 2, bh02, bl02)
    LOADB(0, 3, bh03, bl03)
    LOADB(1, 0, bh10, bl10)
    LOADB(1, 1, bh11, bl11)
    LOADB(1, 2, bh12, bl12)
    LOADB(1, 3, bh13, bl13)
#undef LOADB

    // stage hj rows for this b (coalesced f32x4), once per block
    {
        const int r = t >> 1, hf = t & 1;
        const f32x4* __restrict__ src =
            (const f32x4*)(hj + (b * AA + r) * HH + hf * 32);
        f32x4* dst = (f32x4*)&sHJ[r][hf * 32];
#pragma unroll
        for (int q = 0; q < 8; ++q) dst[q] = src[q];
    }

    // base mask bitsets (diagonal cleared per-i inside the loop)
    const unsigned long long mbase0 = __ballot(mask[b * AA + l] != 0);
    const unsigned long long mbase1 = __ballot(mask[b * AA + 64 + l] != 0);

    __syncthreads();

    // pin B-frags into AGPRs (accum side of the unified file; asm-defined
    // values can't be remat'ed or spill-folded)
#define PIN(v) asm("" : "+a"(v));
    PIN(bh00) PIN(bl00) PIN(bh01) PIN(bl01)
    PIN(bh02) PIN(bl02) PIN(bh03) PIN(bl03)
    PIN(bh10) PIN(bl10) PIN(bh11) PIN(bl11)
    PIN(bh12) PIN(bl12) PIN(bh13) PIN(bl13)
#undef PIN

    const float b2v0 = pb2[col], b2v1 = pb2[32 + col];
    const float w3v0 = pW3[col], w3v1 = pW3[32 + col];
    const float b3s  = pb3[0] * (1.f / 32.f);   // b3 spread over 32 col-lanes

    for (int g = gx; g < ngroups; g += 8) {
        const int slot = g * 4 + wid;
        if (slot >= cnt) continue;            // tail (wave-uniform)
        const int i = __builtin_amdgcn_readfirstlane(jlist[b * AA + slot]);

        // per-i mask bits with diagonal cleared
        unsigned long long mb0 = mbase0, mb1 = mbase1;
        if (i < 64) mb0 &= ~(1ull << i);
        else        mb1 &= ~(1ull << (i - 64));

        // hi row slice for this lane's k-chunks (32 floats)
        const float* __restrict__ hp = hi_p + (b * AA + i) * HH;
        f32x4 yv[8];
#pragma unroll
        for (int ks = 0; ks < 4; ++ks) {
            const int ko = ks * 16 + half * 8;
            yv[2 * ks]     = *(const f32x4*)(hp + ko);
            yv[2 * ks + 1] = *(const f32x4*)(hp + ko + 4);
        }

        float tsum = 0.f;
#pragma unroll
        for (int jt = 0; jt < 4; ++jt) {
            f32x16 acc0 = b2v0, acc1 = b2v1;   // fold pb2 bias into C init
            const int jj = jt * 32 + col;

#define KSTEP(ks, BH0, BL0, BH1, BL1)                                       \
            {   const int ko = (ks) * 16 + half * 8;                        \
                f32x4 x0 = *(const f32x4*)&sHJ[jj][ko];                     \
                f32x4 x1 = *(const f32x4*)&sHJ[jj][ko + 4];                 \
                f32x4 y0 = yv[2 * (ks)], y1 = yv[2 * (ks) + 1];             \
                float h0 = fmaxf(x0[0] + y0[0], 0.f);                       \
                float h1 = fmaxf(x0[1] + y0[1], 0.f);                       \
                float h2 = fmaxf(x0[2] + y0[2], 0.f);                       \
                float h3 = fmaxf(x0[3] + y0[3], 0.f);                       \
                float h4 = fmaxf(x1[0] + y1[0], 0.f);                       \
                float h5 = fmaxf(x1[1] + y1[1], 0.f);                       \
                float h6 = fmaxf(x1[2] + y1[2], 0.f);                       \
                float h7 = fmaxf(x1[3] + y1[3], 0.f);                       \
                unsigned a01, a23, a45, a67, c01, c23, c45, c67;            \
                SPLIT_PAIR(h0, h1, a01, c01)                                \
                SPLIT_PAIR(h2, h3, a23, c23)                                \
                SPLIT_PAIR(h4, h5, a45, c45)                                \
                SPLIT_PAIR(h6, h7, a67, c67)                                \
                uint4v ahv = {a01, a23, a45, a67};                          \
                uint4v alv = {c01, c23, c45, c67};                          \
                bf16x8 ah = __builtin_bit_cast(bf16x8, ahv);                \
                bf16x8 al = __builtin_bit_cast(bf16x8, alv);                \
                acc0 = __builtin_amdgcn_mfma_f32_32x32x16_bf16(             \
                    al, __builtin_bit_cast(bf16x8, BH0), acc0, 0, 0, 0);    \
                acc1 = __builtin_amdgcn_mfma_f32_32x32x16_bf16(             \
                    al, __builtin_bit_cast(bf16x8, BH1), acc1, 0, 0, 0);    \
                acc0 = __builtin_amdgcn_mfma_f32_32x32x16_bf16(             \
                    ah, __builtin_bit_cast(bf16x8, BL0), acc0, 0, 0, 0);    \
                acc1 = __builtin_amdgcn_mfma_f32_32x32x16_bf16(             \
                    ah, __builtin_bit_cast(bf16x8, BL1), acc1, 0, 0, 0);    \
                acc0 = __builtin_amdgcn_mfma_f32_32x32x16_bf16(             \
                    ah, __builtin_bit_cast(bf16x8, BH0), acc0, 0, 0, 0);    \
                acc1 = __builtin_amdgcn_mfma_f32_32x32x16_bf16(             \
                    ah, __builtin_bit_cast(bf16x8, BH1), acc1, 0, 0, 0);    \
            }
            KSTEP(0, bh00, bl00, bh10, bl10)
            KSTEP(1, bh01, bl01, bh11, bl11)
            KSTEP(2, bh02, bl02, bh12, bl12)
            KSTEP(3, bh03, bl03, bh13, bl13)
#undef KSTEP

            // epilogue for this j-tile: W3 contraction + ballot-bit mask
#pragma unroll
            for (int r = 0; r < 16; ++r) {
                const int rrow = (r & 3) + 8 * (r >> 2) + 4 * half;
                float v = fmaxf(acc0[r], 0.f) * w3v0 +
                          fmaxf(acc1[r], 0.f) * w3v1 + b3s;
                const unsigned long long bits = (jt < 2) ? mb0 : mb1;
                const int sh = (jt & 1) * 32 + rrow;
                tsum = fmaf(v, ((bits >> sh) & 1ull) ? 1.f : 0.f, tsum);
            }
        }
#pragma unroll
        for (int off = 32; off; off >>= 1) tsum += __shfl_xor(tsum, off);
        if (l == 0) util[b * AA + i] = base_u[b * AA + i] + tsum;
    }
}

// ---------------- Kernel 3: per-b masked softmax over A=128 ---------------
__global__ __launch_bounds__(64)
void ddc_softmax(const float* __restrict__ util, const int* __restrict__ mask,
                 float* __restrict__ out) {
    const int b = blockIdx.x, lane = threadIdx.x;
    const int r0 = b * AA + lane, r1 = r0 + 64;
    const float u0 = (mask[r0] != 0) ? util[r0] : -1e9f;
    const float u1 = (mask[r1] != 0) ? util[r1] : -1e9f;

    float m = fmaxf(u0, u1);
#pragma unroll
    for (int off = 32; off; off >>= 1) m = fmaxf(m, __shfl_xor(m, off));

    const float e0 = __expf(u0 - m);
    const float e1 = __expf(u1 - m);
    float s = e0 + e1;
#pragma unroll
    for (int off = 32; off; off >>= 1) s += __shfl_xor(s, off);

    const float inv = 1.f / s;
    out[r0] = e0 * inv;
    out[r1] = e1 * inv;
}

extern "C" void kernel_launch(void* const* d_in, const int* in_sizes, int n_in,
                              void* d_out, int out_size, void* d_ws, size_t ws_size,
                              hipStream_t stream) {
    const float* X    = (const float*)d_in[0];
    const int*   mask = (const int*)  d_in[1];
    const float* bW1  = (const float*)d_in[2];
    const float* bb1  = (const float*)d_in[3];
    const float* bW2  = (const float*)d_in[4];
    const float* bb2  = (const float*)d_in[5];
    const float* bW3  = (const float*)d_in[6];
    const float* bb3  = (const float*)d_in[7];
    const float* pW1  = (const float*)d_in[8];
    const float* pb1  = (const float*)d_in[9];
    const float* pW2  = (const float*)d_in[10];
    const float* pb2  = (const float*)d_in[11];
    const float* pW3  = (const float*)d_in[12];
    const float* pb3  = (const float*)d_in[13];

    float* ws    = (float*)d_ws;
    float* hi_p  = ws + OFF_HIP;
    float* hjW   = ws + OFF_HJ;
    float* baseu = ws + OFF_BU;
    float* util  = ws + OFF_UTIL;
    unsigned short* W2fh = (unsigned short*)(ws + OFF_W2FH);
    unsigned short* W2fl = (unsigned short*)(ws + OFF_W2FL);
    int*   jlist = (int*)(ws + OFF_JLIST);
    int*   jcnt  = (int*)(ws + OFF_JCNT);

    float* out = (float*)d_out;

    dim3 g1(AA, BB);
    ddc_features<<<g1, 64, 0, stream>>>(X, mask, bW1, bb1, bW2, bb2, bW3, bb3,
                                        pW1, pb1, pW2,
                                        hi_p, hjW, baseu, W2fh, W2fl,
                                        jlist, jcnt);
    dim3 g2(8, BB);
    ddc_pairs_mfma<<<g2, 256, 0, stream>>>(hi_p, hjW, baseu, mask, jlist, jcnt,
                                           W2fh, W2fl, pb2, pW3, pb3, util);
    ddc_softmax<<<BB, 64, 0, stream>>>(util, mask, out);
}

// Round 12
// 40.222 us; speedup vs baseline: 2.0128x; 1.1428x over previous
//
#include <hip/hip_runtime.h>
#include <hip/hip_bf16.h>

// Sizes (fixed by the reference)
#define BB 64
#define AA 128
#define FF 32
#define HH 64

typedef float  f32x4  __attribute__((ext_vector_type(4)));
typedef float  f32x16 __attribute__((ext_vector_type(16)));
typedef __bf16 bf16x8 __attribute__((ext_vector_type(8)));
typedef unsigned int uint4v __attribute__((ext_vector_type(4)));

// ws layout (float offsets)
#define OFF_HIP   0          // hi_p fp32 [B*A][64]  (pair_b1 folded in)
#define OFF_HJ    524288     // hj   fp32 [B*A][64]
#define OFF_BU    1048576    // base_u [B*A]
#define OFF_UTIL  1056768    // util [B*A]
#define OFF_W2FH  1064960    // W2 frag hi: [8 fid][64 lane][8 ushort] = 8 KB
#define OFF_W2FL  1067008    // W2 frag lo
#define OFF_JLIST 1069056    // active-index list [B][128] int
#define OFF_JCNT  1077248    // [B] int

static __device__ __forceinline__ unsigned short f2b_rne(float x) {
    __hip_bfloat16 h = __float2bfloat16(x);
    return __builtin_bit_cast(unsigned short, h);
}
static __device__ __forceinline__ float b2f(unsigned short u) {
    unsigned v = ((unsigned)u) << 16;
    return __builtin_bit_cast(float, v);
}

// ---------------- Kernel 1: features + active-list + W2 frag split --------
__global__ __launch_bounds__(64)
void ddc_features(const float* __restrict__ X, const int* __restrict__ mask,
                  const float* __restrict__ bW1, const float* __restrict__ bb1,
                  const float* __restrict__ bW2, const float* __restrict__ bb2,
                  const float* __restrict__ bW3, const float* __restrict__ bb3,
                  const float* __restrict__ pW1, const float* __restrict__ pb1,
                  const float* __restrict__ pW2,
                  float* __restrict__ hi_p, float* __restrict__ hj,
                  float* __restrict__ base_u,
                  unsigned short* __restrict__ W2fh,
                  unsigned short* __restrict__ W2fl,
                  int* __restrict__ jlist, int* __restrict__ jcnt) {
    const int a = blockIdx.x, b = blockIdx.y, lane = threadIdx.x;
    const int row = b * AA + a;

    // X row is wave-uniform -> scalar loads
    const float* __restrict__ x = X + row * FF;
    float xr[FF];
#pragma unroll
    for (int f = 0; f < FF; ++f) xr[f] = x[f];

    float vhi = pb1[lane];      // fold pair_b1 into hi
    float vhj = 0.f;
    float v1  = bb1[lane];
#pragma unroll
    for (int f = 0; f < FF; ++f) {
        vhi = fmaf(xr[f], pW1[f * HH + lane], vhi);
        vhj = fmaf(xr[f], pW1[(FF + f) * HH + lane], vhj);
        v1  = fmaf(xr[f], bW1[f * HH + lane], v1);
    }
    v1 = fmaxf(v1, 0.f);

    // hb2 = relu(hb1 @ bW2 + bb2): broadcast hb1 across lanes via shuffles
    float v2 = bb2[lane];
#pragma unroll
    for (int k = 0; k < HH; ++k) {
        float hk = __shfl(v1, k);
        v2 = fmaf(hk, bW2[k * HH + lane], v2);
    }
    v2 = fmaxf(v2, 0.f);

    float bu = v2 * bW3[lane];
#pragma unroll
    for (int off = 32; off; off >>= 1) bu += __shfl_xor(bu, off);

    hi_p[row * HH + lane] = vhi;
    hj  [row * HH + lane] = vhj;
    if (lane == 0) base_u[row] = bu + bb3[0];

    // one block per b builds the compacted active-index list
    if (a == 0) {
        int base0 = 0;
#pragma unroll
        for (int hlf = 0; hlf < 2; ++hlf) {
            int idx = hlf * 64 + lane;
            int m = mask[b * AA + idx];
            unsigned long long bal = __ballot(m != 0);
            int pos = __popcll(bal & ((1ull << lane) - 1ull));
            if (m) jlist[b * AA + base0 + pos] = idx;
            base0 += (int)__popcll(bal);
        }
        if (lane == 0) jcnt[b] = base0;
    }

    // one block writes W2 hi/lo in MFMA B-fragment order:
    // fid = nt*4+ks; lane supplies col n = nt*32+(lane&31),
    // k = ks*16 + (lane>>5)*8 + e  (matches mfma_f32_32x32x16_bf16 B layout)
    if (a == 1 && b == 0) {
        const int col = lane & 31, half = lane >> 5;
#pragma unroll
        for (int fid = 0; fid < 8; ++fid) {
            const int nt = fid >> 2, ks = fid & 3;
            const int n = nt * 32 + col;
            const int ko = ks * 16 + half * 8;
#pragma unroll
            for (int e = 0; e < 8; ++e) {
                float w = pW2[(ko + e) * HH + n];
                unsigned short uh = f2b_rne(w);
                W2fh[(fid * 64 + lane) * 8 + e] = uh;
                W2fl[(fid * 64 + lane) * 8 + e] = f2b_rne(w - b2f(uh));
            }
        }
    }
}

// ---------------- Kernel 2: pairwise MLP via split-bf16 MFMA --------------
// R12 = R11 (persistent grid, AGPR-pinned B-frags, 1 i/wave) + COMPACTED j:
// sHJ stages only the ~cnt active j rows (gathered via jlist); the j-tile
// loop runs ceil(cnt/32) tiles instead of 4 (E ~2.5; mask=Bernoulli(1/2)).
// Diagonal j==i is at compacted index `slot`; tail rows zero-filled and
// epilogue uses a SELECT (not x*0 -- garbage rows may be non-finite).
#define SPLIT_PAIR(pa, pb, outh, outl)                                   \
    {   unsigned ua = __builtin_bit_cast(unsigned, pa);                  \
        unsigned ub = __builtin_bit_cast(unsigned, pb);                  \
        outh = (ua >> 16) | (ub & 0xFFFF0000u);                          \
        float ra = pa - __builtin_bit_cast(float, ua & 0xFFFF0000u);     \
        float rb = pb - __builtin_bit_cast(float, ub & 0xFFFF0000u);     \
        unsigned va = __builtin_bit_cast(unsigned, ra);                  \
        unsigned vb = __builtin_bit_cast(unsigned, rb);                  \
        outl = (va >> 16) | (vb & 0xFFFF0000u); }

__global__ __launch_bounds__(256, 2)
void ddc_pairs_mfma(const float* __restrict__ hi_p, const float* __restrict__ hj,
                    const float* __restrict__ base_u,
                    const int* __restrict__ jlist, const int* __restrict__ jcnt,
                    const unsigned short* __restrict__ W2fh,
                    const unsigned short* __restrict__ W2fl,
                    const float* __restrict__ pb2, const float* __restrict__ pW3,
                    const float* __restrict__ pb3, float* __restrict__ util) {
    __shared__ float sHJ[AA][HH + 4];   // 34816 B

    const int t  = threadIdx.x;
    const int gx = blockIdx.x;            // 0..7
    const int b  = blockIdx.y;
    const int cnt = jcnt[b];
    const int ngroups = (cnt + 3) >> 2;   // groups of 4 i-slots (1 per wave)
    if (gx >= ngroups) return;            // idle block: exit BEFORE staging

    const int l = t & 63, wid = t >> 6;
    const int col = l & 31, half = l >> 5;

    // B-fragment global loads issued FIRST (latency hides under staging);
    // pinned into AGPRs after the barrier.
#define LOADB(nt, ks, vh, vl)                                               \
    uint4v vh = *(const uint4v*)(W2fh + (((nt) * 4 + (ks)) * 64 + l) * 8);  \
    uint4v vl = *(const uint4v*)(W2fl + (((nt) * 4 + (ks)) * 64 + l) * 8);
    LOADB(0, 0, bh00, bl00)
    LOADB(0, 1, bh01, bl01)
    LOADB(0, 2, bh02, bl02)
    LOADB(0, 3, bh03, bl03)
    LOADB(1, 0, bh10, bl10)
    LOADB(1, 1, bh11, bl11)
    LOADB(1, 2, bh12, bl12)
    LOADB(1, 3, bh13, bl13)
#undef LOADB

    // stage COMPACTED hj rows for this b (gather via jlist); zero-fill tail
    {
        const int r = t >> 1, hf = t & 1;
        f32x4* dst = (f32x4*)&sHJ[r][hf * 32];
        if (r < cnt) {
            const int jr = jlist[b * AA + r];
            const f32x4* __restrict__ src =
                (const f32x4*)(hj + (b * AA + jr) * HH + hf * 32);
#pragma unroll
            for (int q = 0; q < 8; ++q) dst[q] = src[q];
        } else {
#pragma unroll
            for (int q = 0; q < 8; ++q) dst[q] = (f32x4)0.f;
        }
    }

    __syncthreads();

    // pin B-frags into AGPRs (accum side of the unified file; asm-defined
    // values can't be remat'ed or spill-folded)
#define PIN(v) asm("" : "+a"(v));
    PIN(bh00) PIN(bl00) PIN(bh01) PIN(bl01)
    PIN(bh02) PIN(bl02) PIN(bh03) PIN(bl03)
    PIN(bh10) PIN(bl10) PIN(bh11) PIN(bl11)
    PIN(bh12) PIN(bl12) PIN(bh13) PIN(bl13)
#undef PIN

    const float b2v0 = pb2[col], b2v1 = pb2[32 + col];
    const float w3v0 = pW3[col], w3v1 = pW3[32 + col];
    const float b3s  = pb3[0] * (1.f / 32.f);   // b3 spread over 32 col-lanes

    const int ntiles = (cnt + 31) >> 5;   // compacted j-tiles

    for (int g = gx; g < ngroups; g += 8) {
        const int slot = g * 4 + wid;
        if (slot >= cnt) continue;            // tail (wave-uniform)
        const int i = __builtin_amdgcn_readfirstlane(jlist[b * AA + slot]);

        // hi row slice for this lane's k-chunks (32 floats)
        const float* __restrict__ hp = hi_p + (b * AA + i) * HH;
        f32x4 yv[8];
#pragma unroll
        for (int ks = 0; ks < 4; ++ks) {
            const int ko = ks * 16 + half * 8;
            yv[2 * ks]     = *(const f32x4*)(hp + ko);
            yv[2 * ks + 1] = *(const f32x4*)(hp + ko + 4);
        }

        float tsum = 0.f;
        for (int jt = 0; jt < ntiles; ++jt) {
            f32x16 acc0 = b2v0, acc1 = b2v1;   // fold pb2 bias into C init
            const int jj = jt * 32 + col;

#define KSTEP(ks, BH0, BL0, BH1, BL1)                                       \
            {   const int ko = (ks) * 16 + half * 8;                        \
                f32x4 x0 = *(const f32x4*)&sHJ[jj][ko];                     \
                f32x4 x1 = *(const f32x4*)&sHJ[jj][ko + 4];                 \
                f32x4 y0 = yv[2 * (ks)], y1 = yv[2 * (ks) + 1];             \
                float h0 = fmaxf(x0[0] + y0[0], 0.f);                       \
                float h1 = fmaxf(x0[1] + y0[1], 0.f);                       \
                float h2 = fmaxf(x0[2] + y0[2], 0.f);                       \
                float h3 = fmaxf(x0[3] + y0[3], 0.f);                       \
                float h4 = fmaxf(x1[0] + y1[0], 0.f);                       \
                float h5 = fmaxf(x1[1] + y1[1], 0.f);                       \
                float h6 = fmaxf(x1[2] + y1[2], 0.f);                       \
                float h7 = fmaxf(x1[3] + y1[3], 0.f);                       \
                unsigned a01, a23, a45, a67, c01, c23, c45, c67;            \
                SPLIT_PAIR(h0, h1, a01, c01)                                \
                SPLIT_PAIR(h2, h3, a23, c23)                                \
                SPLIT_PAIR(h4, h5, a45, c45)                                \
                SPLIT_PAIR(h6, h7, a67, c67)                                \
                uint4v ahv = {a01, a23, a45, a67};                          \
                uint4v alv = {c01, c23, c45, c67};                          \
                bf16x8 ah = __builtin_bit_cast(bf16x8, ahv);                \
                bf16x8 al = __builtin_bit_cast(bf16x8, alv);                \
                acc0 = __builtin_amdgcn_mfma_f32_32x32x16_bf16(             \
                    al, __builtin_bit_cast(bf16x8, BH0), acc0, 0, 0, 0);    \
                acc1 = __builtin_amdgcn_mfma_f32_32x32x16_bf16(             \
                    al, __builtin_bit_cast(bf16x8, BH1), acc1, 0, 0, 0);    \
                acc0 = __builtin_amdgcn_mfma_f32_32x32x16_bf16(             \
                    ah, __builtin_bit_cast(bf16x8, BL0), acc0, 0, 0, 0);    \
                acc1 = __builtin_amdgcn_mfma_f32_32x32x16_bf16(             \
                    ah, __builtin_bit_cast(bf16x8, BL1), acc1, 0, 0, 0);    \
                acc0 = __builtin_amdgcn_mfma_f32_32x32x16_bf16(             \
                    ah, __builtin_bit_cast(bf16x8, BH0), acc0, 0, 0, 0);    \
                acc1 = __builtin_amdgcn_mfma_f32_32x32x16_bf16(             \
                    ah, __builtin_bit_cast(bf16x8, BH1), acc1, 0, 0, 0);    \
            }
            KSTEP(0, bh00, bl00, bh10, bl10)
            KSTEP(1, bh01, bl01, bh11, bl11)
            KSTEP(2, bh02, bl02, bh12, bl12)
            KSTEP(3, bh03, bl03, bh13, bl13)
#undef KSTEP

            // epilogue: W3 contraction; SELECT-zero invalid rows (tail or
            // diagonal slot) -- never multiply (garbage may be non-finite)
#pragma unroll
            for (int r = 0; r < 16; ++r) {
                const int rrow = (r & 3) + 8 * (r >> 2) + 4 * half;
                const int jg = jt * 32 + rrow;
                float v = fmaxf(acc0[r], 0.f) * w3v0 +
                          fmaxf(acc1[r], 0.f) * w3v1 + b3s;
                const bool valid = (jg < cnt) && (jg != slot);
                tsum += valid ? v : 0.f;
            }
        }
#pragma unroll
        for (int off = 32; off; off >>= 1) tsum += __shfl_xor(tsum, off);
        if (l == 0) util[b * AA + i] = base_u[b * AA + i] + tsum;
    }
}

// ---------------- Kernel 3: per-b masked softmax over A=128 ---------------
__global__ __launch_bounds__(64)
void ddc_softmax(const float* __restrict__ util, const int* __restrict__ mask,
                 float* __restrict__ out) {
    const int b = blockIdx.x, lane = threadIdx.x;
    const int r0 = b * AA + lane, r1 = r0 + 64;
    const float u0 = (mask[r0] != 0) ? util[r0] : -1e9f;
    const float u1 = (mask[r1] != 0) ? util[r1] : -1e9f;

    float m = fmaxf(u0, u1);
#pragma unroll
    for (int off = 32; off; off >>= 1) m = fmaxf(m, __shfl_xor(m, off));

    const float e0 = __expf(u0 - m);
    const float e1 = __expf(u1 - m);
    float s = e0 + e1;
#pragma unroll
    for (int off = 32; off; off >>= 1) s += __shfl_xor(s, off);

    const float inv = 1.f / s;
    out[r0] = e0 * inv;
    out[r1] = e1 * inv;
}

extern "C" void kernel_launch(void* const* d_in, const int* in_sizes, int n_in,
                              void* d_out, int out_size, void* d_ws, size_t ws_size,
                              hipStream_t stream) {
    const float* X    = (const float*)d_in[0];
    const int*   mask = (const int*)  d_in[1];
    const float* bW1  = (const float*)d_in[2];
    const float* bb1  = (const float*)d_in[3];
    const float* bW2  = (const float*)d_in[4];
    const float* bb2  = (const float*)d_in[5];
    const float* bW3  = (const float*)d_in[6];
    const float* bb3  = (const float*)d_in[7];
    const float* pW1  = (const float*)d_in[8];
    const float* pb1  = (const float*)d_in[9];
    const float* pW2  = (const float*)d_in[10];
    const float* pb2  = (const float*)d_in[11];
    const float* pW3  = (const float*)d_in[12];
    const float* pb3  = (const float*)d_in[13];

    float* ws    = (float*)d_ws;
    float* hi_p  = ws + OFF_HIP;
    float* hjW   = ws + OFF_HJ;
    float* baseu = ws + OFF_BU;
    float* util  = ws + OFF_UTIL;
    unsigned short* W2fh = (unsigned short*)(ws + OFF_W2FH);
    unsigned short* W2fl = (unsigned short*)(ws + OFF_W2FL);
    int*   jlist = (int*)(ws + OFF_JLIST);
    int*   jcnt  = (int*)(ws + OFF_JCNT);

    float* out = (float*)d_out;

    dim3 g1(AA, BB);
    ddc_features<<<g1, 64, 0, stream>>>(X, mask, bW1, bb1, bW2, bb2, bW3, bb3,
                                        pW1, pb1, pW2,
                                        hi_p, hjW, baseu, W2fh, W2fl,
                                        jlist, jcnt);
    dim3 g2(8, BB);
    ddc_pairs_mfma<<<g2, 256, 0, stream>>>(hi_p, hjW, baseu, jlist, jcnt,
                                           W2fh, W2fl, pb2, pW3, pb3, util);
    ddc_softmax<<<BB, 64, 0, stream>>>(util, mask, out);
}

// Round 13
// 37.968 us; speedup vs baseline: 2.1322x; 1.0594x over previous
//
#include <hip/hip_runtime.h>
#include <hip/hip_bf16.h>

// Sizes (fixed by the reference)
#define BB 64
#define AA 128
#define FF 32
#define HH 64
#define GXDIM 12   // blocks per b: 768 total = 3 blocks/CU (LDS-limited)

typedef float  f32x4  __attribute__((ext_vector_type(4)));
typedef float  f32x16 __attribute__((ext_vector_type(16)));
typedef __bf16 bf16x8 __attribute__((ext_vector_type(8)));
typedef unsigned int uint4v __attribute__((ext_vector_type(4)));

// ws layout (float offsets)
#define OFF_HIP   0          // hi_p fp32 [B*A][64]  (pair_b1 folded in)
#define OFF_HJ    524288     // hj   fp32 [B*A][64]
#define OFF_BU    1048576    // base_u [B*A]
#define OFF_UTIL  1056768    // util [B*A]
#define OFF_W2FH  1064960    // W2 frag hi: [8 fid][64 lane][8 ushort] = 8 KB
#define OFF_W2FL  1067008    // W2 frag lo
#define OFF_JLIST 1069056    // active-index list [B][128] int
#define OFF_JCNT  1077248    // [B] int

static __device__ __forceinline__ unsigned short f2b_rne(float x) {
    __hip_bfloat16 h = __float2bfloat16(x);
    return __builtin_bit_cast(unsigned short, h);
}
static __device__ __forceinline__ float b2f(unsigned short u) {
    unsigned v = ((unsigned)u) << 16;
    return __builtin_bit_cast(float, v);
}

// ---------------- Kernel 1: features + active-list + W2 frag split --------
__global__ __launch_bounds__(64)
void ddc_features(const float* __restrict__ X, const int* __restrict__ mask,
                  const float* __restrict__ bW1, const float* __restrict__ bb1,
                  const float* __restrict__ bW2, const float* __restrict__ bb2,
                  const float* __restrict__ bW3, const float* __restrict__ bb3,
                  const float* __restrict__ pW1, const float* __restrict__ pb1,
                  const float* __restrict__ pW2,
                  float* __restrict__ hi_p, float* __restrict__ hj,
                  float* __restrict__ base_u,
                  unsigned short* __restrict__ W2fh,
                  unsigned short* __restrict__ W2fl,
                  int* __restrict__ jlist, int* __restrict__ jcnt) {
    const int a = blockIdx.x, b = blockIdx.y, lane = threadIdx.x;
    const int row = b * AA + a;

    // X row is wave-uniform -> scalar loads
    const float* __restrict__ x = X + row * FF;
    float xr[FF];
#pragma unroll
    for (int f = 0; f < FF; ++f) xr[f] = x[f];

    float vhi = pb1[lane];      // fold pair_b1 into hi
    float vhj = 0.f;
    float v1  = bb1[lane];
#pragma unroll
    for (int f = 0; f < FF; ++f) {
        vhi = fmaf(xr[f], pW1[f * HH + lane], vhi);
        vhj = fmaf(xr[f], pW1[(FF + f) * HH + lane], vhj);
        v1  = fmaf(xr[f], bW1[f * HH + lane], v1);
    }
    v1 = fmaxf(v1, 0.f);

    // hb2 = relu(hb1 @ bW2 + bb2): broadcast hb1 across lanes via shuffles
    float v2 = bb2[lane];
#pragma unroll
    for (int k = 0; k < HH; ++k) {
        float hk = __shfl(v1, k);
        v2 = fmaf(hk, bW2[k * HH + lane], v2);
    }
    v2 = fmaxf(v2, 0.f);

    float bu = v2 * bW3[lane];
#pragma unroll
    for (int off = 32; off; off >>= 1) bu += __shfl_xor(bu, off);

    hi_p[row * HH + lane] = vhi;
    hj  [row * HH + lane] = vhj;
    if (lane == 0) base_u[row] = bu + bb3[0];

    // one block per b builds the compacted active-index list
    if (a == 0) {
        int base0 = 0;
#pragma unroll
        for (int hlf = 0; hlf < 2; ++hlf) {
            int idx = hlf * 64 + lane;
            int m = mask[b * AA + idx];
            unsigned long long bal = __ballot(m != 0);
            int pos = __popcll(bal & ((1ull << lane) - 1ull));
            if (m) jlist[b * AA + base0 + pos] = idx;
            base0 += (int)__popcll(bal);
        }
        if (lane == 0) jcnt[b] = base0;
    }

    // one block writes W2 hi/lo in MFMA B-fragment order:
    // fid = nt*4+ks; lane supplies col n = nt*32+(lane&31),
    // k = ks*16 + (lane>>5)*8 + e  (matches mfma_f32_32x32x16_bf16 B layout)
    if (a == 1 && b == 0) {
        const int col = lane & 31, half = lane >> 5;
#pragma unroll
        for (int fid = 0; fid < 8; ++fid) {
            const int nt = fid >> 2, ks = fid & 3;
            const int n = nt * 32 + col;
            const int ko = ks * 16 + half * 8;
#pragma unroll
            for (int e = 0; e < 8; ++e) {
                float w = pW2[(ko + e) * HH + n];
                unsigned short uh = f2b_rne(w);
                W2fh[(fid * 64 + lane) * 8 + e] = uh;
                W2fl[(fid * 64 + lane) * 8 + e] = f2b_rne(w - b2f(uh));
            }
        }
    }
}

// ---------------- Kernel 2: pairwise MLP via split-bf16 MFMA --------------
// R13 vs R12: B-fragments move AGPR -> LDS (16 KB staged once per block,
// ds_read_b128 per KSTEP, lane-linear = conflict-free). Accum drops 96->32,
// per-wave total ~150 -> (256,3) gives 3 waves/SIMD (was 2) and grid
// (12,64) = 3 blocks/CU. An opaque-zero offset (asm) inside the jt loop
// keeps LICM from hoisting the 16 B-loads back into registers (R7 trap).
#define SPLIT_PAIR(pa, pb, outh, outl)                                   \
    {   unsigned ua = __builtin_bit_cast(unsigned, pa);                  \
        unsigned ub = __builtin_bit_cast(unsigned, pb);                  \
        outh = (ua >> 16) | (ub & 0xFFFF0000u);                          \
        float ra = pa - __builtin_bit_cast(float, ua & 0xFFFF0000u);     \
        float rb = pb - __builtin_bit_cast(float, ub & 0xFFFF0000u);     \
        unsigned va = __builtin_bit_cast(unsigned, ra);                  \
        unsigned vb = __builtin_bit_cast(unsigned, rb);                  \
        outl = (va >> 16) | (vb & 0xFFFF0000u); }

__global__ __launch_bounds__(256, 3)
void ddc_pairs_mfma(const float* __restrict__ hi_p, const float* __restrict__ hj,
                    const float* __restrict__ base_u,
                    const int* __restrict__ jlist, const int* __restrict__ jcnt,
                    const unsigned short* __restrict__ W2fh,
                    const unsigned short* __restrict__ W2fl,
                    const float* __restrict__ pb2, const float* __restrict__ pW3,
                    const float* __restrict__ pb3, float* __restrict__ util) {
    __shared__ float  sHJ[AA][HH + 4];   // 34816 B
    __shared__ uint4v sBH[512];          // 8192 B  (W2 hi frags)
    __shared__ uint4v sBL[512];          // 8192 B  (W2 lo frags)

    const int t  = threadIdx.x;
    const int gx = blockIdx.x;            // 0..GXDIM-1
    const int b  = blockIdx.y;
    const int cnt = jcnt[b];
    const int ngroups = (cnt + 3) >> 2;   // groups of 4 i-slots (1 per wave)
    if (gx >= ngroups) return;            // idle block: exit BEFORE staging

    const int l = t & 63, wid = t >> 6;
    const int col = l & 31, half = l >> 5;

    // stage B-fragments into LDS (coalesced uint4v)
    {
        const uint4v* __restrict__ gbh = (const uint4v*)W2fh;
        const uint4v* __restrict__ gbl = (const uint4v*)W2fl;
        sBH[t]       = gbh[t];
        sBH[t + 256] = gbh[t + 256];
        sBL[t]       = gbl[t];
        sBL[t + 256] = gbl[t + 256];
    }

    // stage COMPACTED hj rows for this b (gather via jlist); zero-fill tail
    {
        const int r = t >> 1, hf = t & 1;
        f32x4* dst = (f32x4*)&sHJ[r][hf * 32];
        if (r < cnt) {
            const int jr = jlist[b * AA + r];
            const f32x4* __restrict__ src =
                (const f32x4*)(hj + (b * AA + jr) * HH + hf * 32);
#pragma unroll
            for (int q = 0; q < 8; ++q) dst[q] = src[q];
        } else {
#pragma unroll
            for (int q = 0; q < 8; ++q) dst[q] = (f32x4)0.f;
        }
    }

    __syncthreads();

    const float b2v0 = pb2[col], b2v1 = pb2[32 + col];
    const float w3v0 = pW3[col], w3v1 = pW3[32 + col];
    const float b3s  = pb3[0] * (1.f / 32.f);   // b3 spread over 32 col-lanes

    const int ntiles = (cnt + 31) >> 5;   // compacted j-tiles

    for (int g = gx; g < ngroups; g += GXDIM) {
        const int slot = g * 4 + wid;
        if (slot >= cnt) continue;            // tail (wave-uniform)
        const int i = __builtin_amdgcn_readfirstlane(jlist[b * AA + slot]);

        // hi row slice for this lane's k-chunks (32 floats)
        const float* __restrict__ hp = hi_p + (b * AA + i) * HH;
        f32x4 yv[8];
#pragma unroll
        for (int ks = 0; ks < 4; ++ks) {
            const int ko = ks * 16 + half * 8;
            yv[2 * ks]     = *(const f32x4*)(hp + ko);
            yv[2 * ks + 1] = *(const f32x4*)(hp + ko + 4);
        }

        float tsum = 0.f;
        for (int jt = 0; jt < ntiles; ++jt) {
            // opaque zero: makes B-frag LDS addresses loop-variant so LICM
            // cannot hoist the 16 ds_reads into long-lived registers
            unsigned zofs = 0;
            asm volatile("" : "+v"(zofs));

            f32x16 acc0 = b2v0, acc1 = b2v1;   // fold pb2 bias into C init
            const int jj = jt * 32 + col;

#define KSTEP(ks)                                                           \
            {   const int ko = (ks) * 16 + half * 8;                        \
                uint4v bh0 = sBH[(ks) * 64 + l + zofs];                     \
                uint4v bl0 = sBL[(ks) * 64 + l + zofs];                     \
                uint4v bh1 = sBH[(4 + (ks)) * 64 + l + zofs];               \
                uint4v bl1 = sBL[(4 + (ks)) * 64 + l + zofs];               \
                f32x4 x0 = *(const f32x4*)&sHJ[jj][ko];                     \
                f32x4 x1 = *(const f32x4*)&sHJ[jj][ko + 4];                 \
                f32x4 y0 = yv[2 * (ks)], y1 = yv[2 * (ks) + 1];             \
                float h0 = fmaxf(x0[0] + y0[0], 0.f);                       \
                float h1 = fmaxf(x0[1] + y0[1], 0.f);                       \
                float h2 = fmaxf(x0[2] + y0[2], 0.f);                       \
                float h3 = fmaxf(x0[3] + y0[3], 0.f);                       \
                float h4 = fmaxf(x1[0] + y1[0], 0.f);                       \
                float h5 = fmaxf(x1[1] + y1[1], 0.f);                       \
                float h6 = fmaxf(x1[2] + y1[2], 0.f);                       \
                float h7 = fmaxf(x1[3] + y1[3], 0.f);                       \
                unsigned a01, a23, a45, a67, c01, c23, c45, c67;            \
                SPLIT_PAIR(h0, h1, a01, c01)                                \
                SPLIT_PAIR(h2, h3, a23, c23)                                \
                SPLIT_PAIR(h4, h5, a45, c45)                                \
                SPLIT_PAIR(h6, h7, a67, c67)                                \
                uint4v ahv = {a01, a23, a45, a67};                          \
                uint4v alv = {c01, c23, c45, c67};                          \
                bf16x8 ah = __builtin_bit_cast(bf16x8, ahv);                \
                bf16x8 al = __builtin_bit_cast(bf16x8, alv);                \
                acc0 = __builtin_amdgcn_mfma_f32_32x32x16_bf16(             \
                    al, __builtin_bit_cast(bf16x8, bh0), acc0, 0, 0, 0);    \
                acc1 = __builtin_amdgcn_mfma_f32_32x32x16_bf16(             \
                    al, __builtin_bit_cast(bf16x8, bh1), acc1, 0, 0, 0);    \
                acc0 = __builtin_amdgcn_mfma_f32_32x32x16_bf16(             \
                    ah, __builtin_bit_cast(bf16x8, bl0), acc0, 0, 0, 0);    \
                acc1 = __builtin_amdgcn_mfma_f32_32x32x16_bf16(             \
                    ah, __builtin_bit_cast(bf16x8, bl1), acc1, 0, 0, 0);    \
                acc0 = __builtin_amdgcn_mfma_f32_32x32x16_bf16(             \
                    ah, __builtin_bit_cast(bf16x8, bh0), acc0, 0, 0, 0);    \
                acc1 = __builtin_amdgcn_mfma_f32_32x32x16_bf16(             \
                    ah, __builtin_bit_cast(bf16x8, bh1), acc1, 0, 0, 0);    \
            }
            KSTEP(0)
            KSTEP(1)
            KSTEP(2)
            KSTEP(3)
#undef KSTEP

            // epilogue: W3 contraction; SELECT-zero invalid rows (tail or
            // diagonal slot) -- never multiply (garbage may be non-finite)
#pragma unroll
            for (int r = 0; r < 16; ++r) {
                const int rrow = (r & 3) + 8 * (r >> 2) + 4 * half;
                const int jg = jt * 32 + rrow;
                float v = fmaxf(acc0[r], 0.f) * w3v0 +
                          fmaxf(acc1[r], 0.f) * w3v1 + b3s;
                const bool valid = (jg < cnt) && (jg != slot);
                tsum += valid ? v : 0.f;
            }
        }
#pragma unroll
        for (int off = 32; off; off >>= 1) tsum += __shfl_xor(tsum, off);
        if (l == 0) util[b * AA + i] = base_u[b * AA + i] + tsum;
    }
}

// ---------------- Kernel 3: per-b masked softmax over A=128 ---------------
__global__ __launch_bounds__(64)
void ddc_softmax(const float* __restrict__ util, const int* __restrict__ mask,
                 float* __restrict__ out) {
    const int b = blockIdx.x, lane = threadIdx.x;
    const int r0 = b * AA + lane, r1 = r0 + 64;
    const float u0 = (mask[r0] != 0) ? util[r0] : -1e9f;
    const float u1 = (mask[r1] != 0) ? util[r1] : -1e9f;

    float m = fmaxf(u0, u1);
#pragma unroll
    for (int off = 32; off; off >>= 1) m = fmaxf(m, __shfl_xor(m, off));

    const float e0 = __expf(u0 - m);
    const float e1 = __expf(u1 - m);
    float s = e0 + e1;
#pragma unroll
    for (int off = 32; off; off >>= 1) s += __shfl_xor(s, off);

    const float inv = 1.f / s;
    out[r0] = e0 * inv;
    out[r1] = e1 * inv;
}

extern "C" void kernel_launch(void* const* d_in, const int* in_sizes, int n_in,
                              void* d_out, int out_size, void* d_ws, size_t ws_size,
                              hipStream_t stream) {
    const float* X    = (const float*)d_in[0];
    const int*   mask = (const int*)  d_in[1];
    const float* bW1  = (const float*)d_in[2];
    const float* bb1  = (const float*)d_in[3];
    const float* bW2  = (const float*)d_in[4];
    const float* bb2  = (const float*)d_in[5];
    const float* bW3  = (const float*)d_in[6];
    const float* bb3  = (const float*)d_in[7];
    const float* pW1  = (const float*)d_in[8];
    const float* pb1  = (const float*)d_in[9];
    const float* pW2  = (const float*)d_in[10];
    const float* pb2  = (const float*)d_in[11];
    const float* pW3  = (const float*)d_in[12];
    const float* pb3  = (const float*)d_in[13];

    float* ws    = (float*)d_ws;
    float* hi_p  = ws + OFF_HIP;
    float* hjW   = ws + OFF_HJ;
    float* baseu = ws + OFF_BU;
    float* util  = ws + OFF_UTIL;
    unsigned short* W2fh = (unsigned short*)(ws + OFF_W2FH);
    unsigned short* W2fl = (unsigned short*)(ws + OFF_W2FL);
    int*   jlist = (int*)(ws + OFF_JLIST);
    int*   jcnt  = (int*)(ws + OFF_JCNT);

    float* out = (float*)d_out;

    dim3 g1(AA, BB);
    ddc_features<<<g1, 64, 0, stream>>>(X, mask, bW1, bb1, bW2, bb2, bW3, bb3,
                                        pW1, pb1, pW2,
                                        hi_p, hjW, baseu, W2fh, W2fl,
                                        jlist, jcnt);
    dim3 g2(GXDIM, BB);
    ddc_pairs_mfma<<<g2, 256, 0, stream>>>(hi_p, hjW, baseu, jlist, jcnt,
                                           W2fh, W2fl, pb2, pW3, pb3, util);
    ddc_softmax<<<BB, 64, 0, stream>>>(util, mask, out);
}